// Round 9
// baseline (523.133 us; speedup 1.0000x reference)
//
#include <hip/hip_runtime.h>

#define HWS 65536   // 256*256
#define PIT 258     // padded spatial pitch

typedef __attribute__((ext_vector_type(8))) short bf16x8;
typedef __attribute__((ext_vector_type(4))) float f32x4;
typedef unsigned int u32;
typedef unsigned short u16;

__device__ __forceinline__ u16 f2bf(float x) {
    u32 u = __float_as_uint(x);
    return (u16)((u + 0x7fffu + ((u >> 16) & 1u)) >> 16);
}
__device__ __forceinline__ float bf2f(u32 h) { return __uint_as_float(h << 16); }
__device__ __forceinline__ u32 pack2(float a, float b) {
    return (u32)f2bf(a) | ((u32)f2bf(b) << 16);
}

// ---------------- tiny helpers ----------------
__global__ void k_zero(float* __restrict__ p, int n) {
    int i = blockIdx.x * 256 + threadIdx.x;
    if (i < n) p[i] = 0.f;
}

// zero the 1-pixel border of the padded xT planes (1028 border tokens x 64 ci)
__global__ void k_border(u16* __restrict__ xTr, u16* __restrict__ xTi) {
    int gid = blockIdx.x * 256 + threadIdx.x;
    if (gid >= 8224) return;                  // 1028 tokens * 8 uint4
    int t = gid >> 3, j = gid & 7;
    int tok;
    if (t < 258)       tok = t;                         // top row
    else if (t < 516)  tok = 257 * PIT + (t - 258);     // bottom row
    else if (t < 772)  tok = (t - 515) * PIT;           // left col, rows 1..256
    else               tok = (t - 771) * PIT + 257;     // right col
    uint4 z = make_uint4(0, 0, 0, 0);
    *(uint4*)&xTr[(size_t)tok * 64 + j * 8] = z;
    *(uint4*)&xTi[(size_t)tok * 64 + j * 8] = z;
}

// ---------------- fold dw (3x3, per-channel complex) into qkv 1x1 weights ----------------
// WB planes [3][9][192][64] bf16: plane0 = Re(wdw*wq), plane1 = Im, plane2 = -Im
__global__ void k_fold(const float* __restrict__ qr, const float* __restrict__ qi,
                       const float* __restrict__ dr, const float* __restrict__ di,
                       u16* __restrict__ WB) {
    int i = blockIdx.x * 256 + threadIdx.x;   // over 9*192*64
    if (i >= 110592) return;
    int ci = i & 63; int rem = i >> 6; int co = rem % 192; int tap = rem / 192;
    float a = dr[co * 9 + tap], b = di[co * 9 + tap];
    float c = qr[co * 64 + ci], d = qi[co * 64 + ci];
    float re = a * c - b * d, im = a * d + b * c;
    WB[(0 * 9 + tap) * 12288 + co * 64 + ci] = f2bf(re);
    WB[(1 * 9 + tap) * 12288 + co * 64 + ci] = f2bf(im);
    WB[(2 * 9 + tap) * 12288 + co * 64 + ci] = f2bf(-im);
}

// ---------------- Kernel X: transpose+convert x -> padded xTr/xTi bf16 [PIT*PIT][64] ----------------
__global__ __launch_bounds__(256) void k_xt(const float* __restrict__ x,
                                            u16* __restrict__ xTr,
                                            u16* __restrict__ xTi) {
    __shared__ u16 Tr[64][73], Ti[64][73];
    int p0 = blockIdx.x << 6;
    int w = p0 >> 8, h0 = p0 & 255;           // 64-token tile, single image row
    int t = threadIdx.x;
    const float2* x2 = (const float2*)x;
    for (int i = t; i < 4096; i += 256) {
        int ci = i >> 6, c = i & 63;
        float2 v = x2[(size_t)ci * HWS + p0 + c];
        Tr[c][ci] = f2bf(v.x);
        Ti[c][ci] = f2bf(v.y);
    }
    __syncthreads();
    size_t dbase = ((size_t)(w + 1) * PIT + h0 + 1) * 64;
    for (int i = t; i < 4096; i += 256) {
        int rr = i >> 6, ci = i & 63;
        xTr[dbase + (size_t)rr * 64 + ci] = Tr[rr][ci];
        xTi[dbase + (size_t)rr * 64 + ci] = Ti[rr][ci];
    }
}

// ---------------- Kernel C: fused (qkv 1x1 + depthwise 3x3), pure global->MFMA ----------------
// xTr/xTi padded [PIT*PIT][64]; WB [3][9][192][64]; q,k -> dwp planes [4][64][HWS] u16;
// v -> vpack [64][HWS] u32. Grid 1536 (XCD-swizzled rows), 256 thr.
__global__ __launch_bounds__(256) void k_conv(const u16* __restrict__ xTr,
                                              const u16* __restrict__ xTi,
                                              const u16* __restrict__ WB,
                                              u16* __restrict__ dwp,
                                              u32* __restrict__ vpack) {
    __shared__ u32 Tep[32][257];                // epilogue transpose only

    const int wg = blockIdx.x;
    const int xcd = wg & 7, idx = wg >> 3;      // rows 32k..32k+31 stay on XCD k
    const int row = xcd * 32 + (idx & 31);
    const int cog = idx >> 5;                   // 0..5 -> 32 co each
    const int t = threadIdx.x, lane = t & 63, wv = t >> 6;
    const int l15 = lane & 15, l4 = lane >> 4;

    const f32x4 zz = {0.f, 0.f, 0.f, 0.f};
    f32x4 cr[2][4], ci2[2][4];
#pragma unroll
    for (int cf = 0; cf < 2; ++cf)
#pragma unroll
        for (int pf = 0; pf < 4; ++pf) { cr[cf][pf] = zz; ci2[cf][pf] = zz; }

    const int hbase = wv * 64 + l15;            // + pf*16 + ct

    for (int rt = 0; rt < 3; ++rt) {
        const size_t rowbase = (size_t)(row + rt) * PIT;   // padded row index
#pragma unroll
        for (int ct = 0; ct < 3; ++ct) {
            const int tap = rt * 3 + ct;
            bf16x8 Ar[2][2], Ai[2][2], An[2][2];
#pragma unroll
            for (int cf = 0; cf < 2; ++cf)
#pragma unroll
                for (int ks = 0; ks < 2; ++ks) {
                    size_t aoff = (size_t)(tap * 192 + cog * 32 + 16 * cf + l15) * 64
                                  + 32 * ks + 8 * l4;
                    Ar[cf][ks] = *(const bf16x8*)&WB[aoff];
                    Ai[cf][ks] = *(const bf16x8*)&WB[110592 + aoff];
                    An[cf][ks] = *(const bf16x8*)&WB[221184 + aoff];
                }
#pragma unroll
            for (int pf = 0; pf < 4; ++pf) {
                size_t tk = (rowbase + hbase + pf * 16 + ct) * 64 + 8 * l4;
                bf16x8 br[2], bi[2];
                br[0] = *(const bf16x8*)&xTr[tk];
                br[1] = *(const bf16x8*)&xTr[tk + 32];
                bi[0] = *(const bf16x8*)&xTi[tk];
                bi[1] = *(const bf16x8*)&xTi[tk + 32];
#pragma unroll
                for (int ks = 0; ks < 2; ++ks)
#pragma unroll
                    for (int cf = 0; cf < 2; ++cf) {
                        cr[cf][pf]  = __builtin_amdgcn_mfma_f32_16x16x32_bf16(Ar[cf][ks], br[ks], cr[cf][pf], 0, 0, 0);
                        cr[cf][pf]  = __builtin_amdgcn_mfma_f32_16x16x32_bf16(An[cf][ks], bi[ks], cr[cf][pf], 0, 0, 0);
                        ci2[cf][pf] = __builtin_amdgcn_mfma_f32_16x16x32_bf16(Ai[cf][ks], br[ks], ci2[cf][pf], 0, 0, 0);
                        ci2[cf][pf] = __builtin_amdgcn_mfma_f32_16x16x32_bf16(Ar[cf][ks], bi[ks], ci2[cf][pf], 0, 0, 0);
                    }
            }
        }
    }

    // ---------- epilogue: LDS transpose -> wide coalesced stores ----------
    __syncthreads();
#pragma unroll
    for (int cf = 0; cf < 2; ++cf)
#pragma unroll
        for (int pf = 0; pf < 4; ++pf)
#pragma unroll
            for (int r = 0; r < 4; ++r) {
                int col = 16 * cf + 4 * l4 + r;          // local co 0..31
                int tok = wv * 64 + pf * 16 + l15;       // local token 0..255
                Tep[col][tok] = pack2(cr[cf][pf][r], ci2[cf][pf][r]);
            }
    __syncthreads();

    const int co_l = t & 31, seg = (t >> 5) << 5;        // conflict-free map
    u32 vb[32];
#pragma unroll
    for (int j = 0; j < 32; ++j) vb[j] = Tep[co_l][seg + j];
    const int token0 = row * 256 + seg;

    if (cog < 4) {                               // q,k -> split r/i planes, 2 tok per u32
        int co = cog * 32 + co_l;
        int pl = (co < 64) ? 0 : 2;
        int c2 = co & 63;
        u32 rw[16], iw[16];
#pragma unroll
        for (int j = 0; j < 16; ++j) {
            rw[j] = (vb[2 * j] & 0xFFFFu) | (vb[2 * j + 1] << 16);
            iw[j] = (vb[2 * j] >> 16) | (vb[2 * j + 1] & 0xFFFF0000u);
        }
        uint4* dr_ = (uint4*)&dwp[(size_t)(pl * 64 + c2) * HWS + token0];
        uint4* di_ = (uint4*)&dwp[(size_t)((pl + 1) * 64 + c2) * HWS + token0];
#pragma unroll
        for (int j = 0; j < 4; ++j) {
            dr_[j] = make_uint4(rw[4 * j], rw[4 * j + 1], rw[4 * j + 2], rw[4 * j + 3]);
            di_[j] = make_uint4(iw[4 * j], iw[4 * j + 1], iw[4 * j + 2], iw[4 * j + 3]);
        }
    } else {                                     // v -> vpack [e][HWS] u32
        int e = (cog - 4) * 32 + co_l;
        uint4* dst = (uint4*)&vpack[(size_t)e * HWS + token0];
#pragma unroll
        for (int j = 0; j < 8; ++j)
            dst[j] = make_uint4(vb[4 * j], vb[4 * j + 1], vb[4 * j + 2], vb[4 * j + 3]);
    }
}

// ---------------- Kernel C2: q k^T + fused sumsq via MFMA (no LDS) ----------------
__global__ __launch_bounds__(256) void k_qk(const u16* __restrict__ dwp,
                                            float* __restrict__ rnsum,
                                            float* __restrict__ attn,
                                            int b, int SP) {
    const int chunk = blockIdx.x;        // 0..31
    const int d = blockIdx.y;
    const int Kc = SP >> 5;
    const int kc0 = chunk * Kc;
    const u16* qp = dwp + (size_t)d * 64 * SP;
    const u16* kp = dwp + (size_t)(2 + d) * 64 * SP;

    const int t = threadIdx.x, lane = t & 63, wid = t >> 6;
    const int wy = wid >> 1, wx = wid & 1;
    const int l15 = lane & 15, l4 = lane >> 4;

    f32x4 zz = {0.f, 0.f, 0.f, 0.f};
    f32x4 acc[2][2] = {{zz, zz}, {zz, zz}};
    float sq[2] = {0.f, 0.f}, sk[2] = {0.f, 0.f};

    const int iters = Kc >> 5;
    for (int ks = 0; ks < iters; ++ks) {
        int k0 = kc0 + ks * 32 + 8 * l4;
        bf16x8 aq[2], bk[2];
#pragma unroll
        for (int cf = 0; cf < 2; ++cf)
            aq[cf] = *(const bf16x8*)&qp[(size_t)(32 * wy + 16 * cf + l15) * SP + k0];
#pragma unroll
        for (int ef = 0; ef < 2; ++ef)
            bk[ef] = *(const bf16x8*)&kp[(size_t)(32 * wx + 16 * ef + l15) * SP + k0];

        if (wx == 0)
#pragma unroll
            for (int cf = 0; cf < 2; ++cf)
#pragma unroll
                for (int j = 0; j < 8; ++j) {
                    float f = bf2f((u16)aq[cf][j]);
                    sq[cf] = fmaf(f, f, sq[cf]);
                }
        if (wy == 0)
#pragma unroll
            for (int ef = 0; ef < 2; ++ef)
#pragma unroll
                for (int j = 0; j < 8; ++j) {
                    float f = bf2f((u16)bk[ef][j]);
                    sk[ef] = fmaf(f, f, sk[ef]);
                }

#pragma unroll
        for (int cf = 0; cf < 2; ++cf)
#pragma unroll
            for (int ef = 0; ef < 2; ++ef)
                acc[cf][ef] = __builtin_amdgcn_mfma_f32_16x16x32_bf16(aq[cf], bk[ef], acc[cf][ef], 0, 0, 0);
    }

#pragma unroll
    for (int cf = 0; cf < 2; ++cf)
#pragma unroll
        for (int ef = 0; ef < 2; ++ef)
#pragma unroll
            for (int r = 0; r < 4; ++r) {
                int cq = 32 * wy + 16 * cf + 4 * l4 + r;
                int ce = 32 * wx + 16 * ef + l15;
                atomicAdd(&attn[((b * 2 + d) * 64 + cq) * 64 + ce], acc[cf][ef][r]);
            }

    if (wx == 0)
#pragma unroll
        for (int cf = 0; cf < 2; ++cf) {
            float v = sq[cf];
            v += __shfl_xor(v, 16);
            v += __shfl_xor(v, 32);
            if (lane < 16)
                atomicAdd(&rnsum[((size_t)b * 128 + 32 * wy + 16 * cf + lane) * 2 + d], v);
        }
    if (wy == 0)
#pragma unroll
        for (int ef = 0; ef < 2; ++ef) {
            float v = sk[ef];
            v += __shfl_xor(v, 16);
            v += __shfl_xor(v, 32);
            if (lane < 16)
                atomicAdd(&rnsum[((size_t)b * 128 + 64 + 32 * wx + 16 * ef + lane) * 2 + d], v);
        }
}

// ---------------- Kernel D1: scale + row softmax -> P ----------------
__global__ __launch_bounds__(64) void k_prob(const float* __restrict__ attn,
                                             const float* __restrict__ rnsum,
                                             float* __restrict__ P, int b) {
    int d = blockIdx.x;
    int t = threadIdx.x;
    __shared__ float rks[64];
    float sk = rnsum[((size_t)b * 128 + 64 + t) * 2 + d];
    rks[t] = 1.0f / fmaxf(sqrtf(sk), 1e-12f);
    float sq = rnsum[((size_t)b * 128 + t) * 2 + d];
    float rq = 1.0f / fmaxf(sqrtf(sq), 1e-12f);
    __syncthreads();

    const float* arow = attn + ((size_t)(b * 2 + d) * 64 + t) * 64;
    float v[64];
    float m = -1e30f;
#pragma unroll
    for (int e = 0; e < 64; ++e) { v[e] = arow[e] * rq * rks[e]; m = fmaxf(m, v[e]); }
    float ssum = 0.f;
#pragma unroll
    for (int e = 0; e < 64; ++e) { v[e] = __expf(v[e] - m); ssum += v[e]; }
    float r = 1.0f / ssum;
    float* prow = P + ((size_t)(b * 2 + d) * 64 + t) * 64;
#pragma unroll
    for (int e = 0; e < 64; ++e) prow[e] = v[e] * r;
}

// ---------------- Kernel D2: build A_big from P and proj weights ----------------
__global__ __launch_bounds__(256) void k_M(const float* __restrict__ P,
                                           const float* __restrict__ pwr,
                                           const float* __restrict__ pwi,
                                           u16* __restrict__ Abig, int b) {
    int pair = blockIdx.x * 256 + threadIdx.x;   // 0..4095
    __shared__ float P0[64][64], P1[64][64];
    __shared__ float Wr[64][64], Wi2[64][64];
    for (int i = threadIdx.x; i < 4096; i += 256) {
        P0[i >> 6][i & 63] = P[(size_t)(b * 2 + 0) * 4096 + i];
        P1[i >> 6][i & 63] = P[(size_t)(b * 2 + 1) * 4096 + i];
        Wr[i >> 6][i & 63] = pwr[i];
        Wi2[i >> 6][i & 63] = pwi[i];
    }
    __syncthreads();
    int co = pair >> 6, e = pair & 63;
    float m1 = 0.f, m2 = 0.f, m3 = 0.f, m4 = 0.f;
#pragma unroll 8
    for (int c = 0; c < 64; ++c) {
        float pr = Wr[co][c], pi = Wi2[co][c];
        float a0 = P0[c][e], a1 = P1[c][e];
        m1 = fmaf(pr, a0, m1);
        m2 = fmaf(pi, a1, m2);
        m3 = fmaf(pr, a1, m3);
        m4 = fmaf(pi, a0, m4);
    }
    u16* AB = Abig + (size_t)b * 16384;
    AB[(2 * co) * 128 + 2 * e]         = f2bf(m1);
    AB[(2 * co) * 128 + 2 * e + 1]     = f2bf(-m2);
    AB[(2 * co + 1) * 128 + 2 * e]     = f2bf(m4);
    AB[(2 * co + 1) * 128 + 2 * e + 1] = f2bf(m3);
}

// ---------------- Kernel E: transpose vpack [64][HWS] u32 -> vT [HWS][64] u32 ----------------
__global__ __launch_bounds__(256) void k_vt(const u32* __restrict__ in,
                                            u32* __restrict__ outp) {
    __shared__ u32 tile[64][65];
    int p0 = blockIdx.x << 6;
    int t = threadIdx.x;
    for (int i = t; i < 4096; i += 256) {
        int e = i >> 6, c = i & 63;
        tile[e][c] = in[(size_t)e * HWS + p0 + c];
    }
    __syncthreads();
    for (int i = t; i < 4096; i += 256) {
        int r = i >> 6, e = i & 63;
        outp[(size_t)(p0 + r) * 64 + e] = tile[e][r];
    }
}

// ---------------- Kernel F: out = A_big * vT via MFMA (no LDS) ----------------
__global__ __launch_bounds__(256) void k_out(const u16* __restrict__ Abig,
                                             const u16* __restrict__ vT,
                                             float* __restrict__ outb) {
    const int p0 = blockIdx.x << 6;
    const int t = threadIdx.x, lane = t & 63, w = t >> 6;
    const int l15 = lane & 15, l4 = lane >> 4;

    bf16x8 Af[2][4];
#pragma unroll
    for (int cf = 0; cf < 2; ++cf)
#pragma unroll
        for (int ks = 0; ks < 4; ++ks)
            Af[cf][ks] = *(const bf16x8*)&Abig[(size_t)(32 * w + 16 * cf + l15) * 128 + 32 * ks + 8 * l4];

    f32x4 zz = {0.f, 0.f, 0.f, 0.f};
    f32x4 acc[2][4];
#pragma unroll
    for (int cf = 0; cf < 2; ++cf)
#pragma unroll
        for (int nf = 0; nf < 4; ++nf) acc[cf][nf] = zz;

#pragma unroll
    for (int ks = 0; ks < 4; ++ks) {
        bf16x8 Bf[4];
#pragma unroll
        for (int nf = 0; nf < 4; ++nf)
            Bf[nf] = *(const bf16x8*)&vT[(size_t)(p0 + 16 * nf + l15) * 128 + 32 * ks + 8 * l4];
#pragma unroll
        for (int cf = 0; cf < 2; ++cf)
#pragma unroll
            for (int nf = 0; nf < 4; ++nf)
                acc[cf][nf] = __builtin_amdgcn_mfma_f32_16x16x32_bf16(Af[cf][ks], Bf[nf], acc[cf][nf], 0, 0, 0);
    }

    float2* o2 = (float2*)outb;
#pragma unroll
    for (int cf = 0; cf < 2; ++cf)
#pragma unroll
        for (int nf = 0; nf < 4; ++nf) {
            int co = 16 * w + 8 * cf + 2 * l4;
            int p = p0 + 16 * nf + l15;
            o2[(size_t)co * HWS + p]       = make_float2(acc[cf][nf][0], acc[cf][nf][1]);
            o2[(size_t)(co + 1) * HWS + p] = make_float2(acc[cf][nf][2], acc[cf][nf][3]);
        }
}

extern "C" void kernel_launch(void* const* d_in, const int* in_sizes, int n_in,
                              void* d_out, int out_size, void* d_ws, size_t ws_size,
                              hipStream_t stream) {
    const float* x      = (const float*)d_in[0];
    const float* qkv_wr = (const float*)d_in[1];
    const float* qkv_wi = (const float*)d_in[2];
    const float* dw_wr  = (const float*)d_in[3];
    const float* dw_wi  = (const float*)d_in[4];
    const float* p_wr   = (const float*)d_in[5];
    const float* p_wi   = (const float*)d_in[6];
    float* out = (float*)d_out;

    // workspace (~68.1 MB)
    char* base = (char*)d_ws;
    const size_t xt_sz = (size_t)PIT * PIT * 64 * 2;       // 8,520,192 B (padded plane)
    u16*   dwp  = (u16*)base;                              // 33,554,432 B
    u16*   xTr  = (u16*)(base + 33554432);
    u16*   xTi  = (u16*)(base + 33554432 + xt_sz);
    u32*   vT   = (u32*)(base + 33554432 + 2 * xt_sz);     // 16,777,216 B
    u16*   WB   = (u16*)(base + 33554432 + 2 * xt_sz + 16777216);   // 663,552 B
    float* rnsum = (float*)((char*)WB + 663552);
    float* attn  = rnsum + 512;
    float* Pbuf  = attn + 16384;
    u16*   Abig  = (u16*)(Pbuf + 16384);

    k_fold<<<432, 256, 0, stream>>>(qkv_wr, qkv_wi, dw_wr, dw_wi, WB);
    k_zero<<<66, 256, 0, stream>>>(rnsum, 512 + 16384);
    k_border<<<33, 256, 0, stream>>>(xTr, xTi);

    for (int b = 0; b < 2; ++b) {
        const float* xb = x + (size_t)b * 64 * HWS * 2;
        u32* vpack = (u32*)(out + (size_t)b * 64 * HWS * 2);   // scratch inside d_out
        k_xt<<<1024, 256, 0, stream>>>(xb, xTr, xTi);
        k_conv<<<1536, 256, 0, stream>>>(xTr, xTi, WB, dwp, vpack);
        k_qk<<<dim3(32, 2), 256, 0, stream>>>(dwp, rnsum, attn, b, HWS);
        k_prob<<<2, 64, 0, stream>>>(attn, rnsum, Pbuf, b);
        k_M<<<16, 256, 0, stream>>>(Pbuf, p_wr, p_wi, Abig, b);
        k_vt<<<1024, 256, 0, stream>>>(vpack, vT);
        k_out<<<1024, 256, 0, stream>>>(Abig + (size_t)b * 16384, (const u16*)vT,
                                        out + (size_t)b * 64 * HWS * 2);
    }
}

// Round 10
// 405.959 us; speedup vs baseline: 1.2886x; 1.2886x over previous
//
#include <hip/hip_runtime.h>

#define HWS 65536   // 256*256
#define PIT 258     // padded spatial pitch

typedef __attribute__((ext_vector_type(8))) short bf16x8;
typedef __attribute__((ext_vector_type(4))) float f32x4;
typedef unsigned int u32;
typedef unsigned short u16;

__device__ __forceinline__ u16 f2bf(float x) {
    u32 u = __float_as_uint(x);
    return (u16)((u + 0x7fffu + ((u >> 16) & 1u)) >> 16);
}
__device__ __forceinline__ float bf2f(u32 h) { return __uint_as_float(h << 16); }
__device__ __forceinline__ u32 pack2(float a, float b) {
    return (u32)f2bf(a) | ((u32)f2bf(b) << 16);
}

// ---------------- tiny helpers ----------------
__global__ void k_zero(float* __restrict__ p, int n) {
    int i = blockIdx.x * 256 + threadIdx.x;
    if (i < n) p[i] = 0.f;
}

// zero the 1-pixel border of the padded xT planes
__global__ void k_border(u16* __restrict__ xTr, u16* __restrict__ xTi) {
    int gid = blockIdx.x * 256 + threadIdx.x;
    if (gid >= 8224) return;                  // 1028 border tokens * 8 uint4
    int t = gid >> 3, j = gid & 7;
    int tok;
    if (t < 258)       tok = t;                         // top row
    else if (t < 516)  tok = 257 * PIT + (t - 258);     // bottom row
    else if (t < 772)  tok = (t - 515) * PIT;           // left col, rows 1..256
    else               tok = (t - 771) * PIT + 257;     // right col
    uint4 z = make_uint4(0, 0, 0, 0);
    *(uint4*)&xTr[(size_t)tok * 64 + j * 8] = z;
    *(uint4*)&xTi[(size_t)tok * 64 + j * 8] = z;
}

// ---------------- fold dw (3x3, per-channel complex) into qkv 1x1 weights ----------------
// WB planes [3][9][192][64] bf16: plane0 = Re(wdw*wq), plane1 = Im, plane2 = -Im
__global__ void k_fold(const float* __restrict__ qr, const float* __restrict__ qi,
                       const float* __restrict__ dr, const float* __restrict__ di,
                       u16* __restrict__ WB) {
    int i = blockIdx.x * 256 + threadIdx.x;   // over 9*192*64
    if (i >= 110592) return;
    int ci = i & 63; int rem = i >> 6; int co = rem % 192; int tap = rem / 192;
    float a = dr[co * 9 + tap], b = di[co * 9 + tap];
    float c = qr[co * 64 + ci], d = qi[co * 64 + ci];
    float re = a * c - b * d, im = a * d + b * c;
    WB[(0 * 9 + tap) * 12288 + co * 64 + ci] = f2bf(re);
    WB[(1 * 9 + tap) * 12288 + co * 64 + ci] = f2bf(im);
    WB[(2 * 9 + tap) * 12288 + co * 64 + ci] = f2bf(-im);
}

// ---------------- Kernel X: transpose+convert x -> padded xTr/xTi bf16 [PIT*PIT][64] ----------------
__global__ __launch_bounds__(256) void k_xt(const float* __restrict__ x,
                                            u16* __restrict__ xTr,
                                            u16* __restrict__ xTi) {
    __shared__ u16 Tr[64][73], Ti[64][73];
    int p0 = blockIdx.x << 6;
    int w = p0 >> 8, h0 = p0 & 255;
    int t = threadIdx.x;
    const float2* x2 = (const float2*)x;
    for (int i = t; i < 4096; i += 256) {
        int ci = i >> 6, c = i & 63;
        float2 v = x2[(size_t)ci * HWS + p0 + c];
        Tr[c][ci] = f2bf(v.x);
        Ti[c][ci] = f2bf(v.y);
    }
    __syncthreads();
    size_t dbase = ((size_t)(w + 1) * PIT + h0 + 1) * 64;
    for (int i = t; i < 4096; i += 256) {
        int rr = i >> 6, ci = i & 63;
        xTr[dbase + (size_t)rr * 64 + ci] = Tr[rr][ci];
        xTi[dbase + (size_t)rr * 64 + ci] = Ti[rr][ci];
    }
}

// ---------------- Kernel C: fused conv, LDS-staged A (fragment-linear) + padded global B ----------------
// q,k -> dwp planes [4][64][HWS] u16; v -> vT [HWS][64] u32 directly.
__global__ __launch_bounds__(256) void k_conv(const u16* __restrict__ xTr,
                                              const u16* __restrict__ xTi,
                                              const u16* __restrict__ WB,
                                              u16* __restrict__ dwp,
                                              u32* __restrict__ vT) {
    __shared__ __align__(16) char smem[36992];   // AsmF 36 KB | Tep 32x257 u32 (reused)
    u32* Tep = (u32*)smem;

    const int wg = blockIdx.x;
    const int xcd = wg & 7, idx = wg >> 3;      // rows 32k..32k+31 stay on XCD k
    const int row = xcd * 32 + (idx & 31);
    const int cog = idx >> 5;                   // 0..5 -> 32 co each
    const int t = threadIdx.x, lane = t & 63, wv = t >> 6;
    const int l15 = lane & 15, l4 = lane >> 4;

    const f32x4 zz = {0.f, 0.f, 0.f, 0.f};
    f32x4 cr[2][4], ci2[2][4];
#pragma unroll
    for (int cf = 0; cf < 2; ++cf)
#pragma unroll
        for (int pf = 0; pf < 4; ++pf) { cr[cf][pf] = zz; ci2[cf][pf] = zz; }

    const int hbase = wv * 64 + l15;

    for (int rt = 0; rt < 3; ++rt) {
        const size_t rowbase = (size_t)(row + rt) * PIT;
        __syncthreads();
        // stage 36 fragments (3ct x 3plane x 2cf x 2ks), fragment-linear: fid*1024 + lane*16
        for (int i = t; i < 2304; i += 256) {
            int fid = i >> 6, ln = i & 63;
            int ks = fid & 1, cf = (fid >> 1) & 1;
            int tp = fid >> 2;                  // ct*3 + plane
            int plane = tp % 3, ct = tp / 3;
            size_t src = (size_t)plane * 110592 + (size_t)(rt * 3 + ct) * 12288
                       + (size_t)(cog * 32 + 16 * cf + (ln & 15)) * 64
                       + 32 * ks + 8 * (ln >> 4);
            *(uint4*)&smem[(ct * 12 + plane * 4 + cf * 2 + ks) * 1024 + ln * 16] =
                *(const uint4*)&WB[src];
        }
        __syncthreads();

#pragma unroll
        for (int ct = 0; ct < 3; ++ct) {
            const int cb = ct * 12288;
            bf16x8 Ar[2][2], Ai[2][2], An[2][2];
#pragma unroll
            for (int cf = 0; cf < 2; ++cf)
#pragma unroll
                for (int ks = 0; ks < 2; ++ks) {
                    Ar[cf][ks] = *(const bf16x8*)&smem[cb + (0 * 4 + cf * 2 + ks) * 1024 + lane * 16];
                    Ai[cf][ks] = *(const bf16x8*)&smem[cb + (1 * 4 + cf * 2 + ks) * 1024 + lane * 16];
                    An[cf][ks] = *(const bf16x8*)&smem[cb + (2 * 4 + cf * 2 + ks) * 1024 + lane * 16];
                }
#pragma unroll
            for (int pf = 0; pf < 4; ++pf) {
                size_t tk = (rowbase + hbase + pf * 16 + ct) * 64 + 8 * l4;
                bf16x8 br[2], bi[2];
                br[0] = *(const bf16x8*)&xTr[tk];
                br[1] = *(const bf16x8*)&xTr[tk + 32];
                bi[0] = *(const bf16x8*)&xTi[tk];
                bi[1] = *(const bf16x8*)&xTi[tk + 32];
#pragma unroll
                for (int ks = 0; ks < 2; ++ks)
#pragma unroll
                    for (int cf = 0; cf < 2; ++cf) {
                        cr[cf][pf]  = __builtin_amdgcn_mfma_f32_16x16x32_bf16(Ar[cf][ks], br[ks], cr[cf][pf], 0, 0, 0);
                        cr[cf][pf]  = __builtin_amdgcn_mfma_f32_16x16x32_bf16(An[cf][ks], bi[ks], cr[cf][pf], 0, 0, 0);
                        ci2[cf][pf] = __builtin_amdgcn_mfma_f32_16x16x32_bf16(Ai[cf][ks], br[ks], ci2[cf][pf], 0, 0, 0);
                        ci2[cf][pf] = __builtin_amdgcn_mfma_f32_16x16x32_bf16(Ar[cf][ks], bi[ks], ci2[cf][pf], 0, 0, 0);
                    }
            }
        }
    }

    if (cog >= 4) {
        // v: store straight to vT [token][64] u32 -- 8 x uint4 per thread, no LDS
#pragma unroll
        for (int cf = 0; cf < 2; ++cf)
#pragma unroll
            for (int pf = 0; pf < 4; ++pf) {
                int token = row * 256 + wv * 64 + pf * 16 + l15;
                int e0 = (cog - 4) * 32 + 16 * cf + 4 * l4;
                uint4 vv = make_uint4(pack2(cr[cf][pf][0], ci2[cf][pf][0]),
                                      pack2(cr[cf][pf][1], ci2[cf][pf][1]),
                                      pack2(cr[cf][pf][2], ci2[cf][pf][2]),
                                      pack2(cr[cf][pf][3], ci2[cf][pf][3]));
                *(uint4*)&vT[(size_t)token * 64 + e0] = vv;
            }
        return;
    }

    // ---------- q,k epilogue: LDS transpose -> wide coalesced stores ----------
    __syncthreads();
#pragma unroll
    for (int cf = 0; cf < 2; ++cf)
#pragma unroll
        for (int pf = 0; pf < 4; ++pf)
#pragma unroll
            for (int r = 0; r < 4; ++r) {
                int col = 16 * cf + 4 * l4 + r;          // local co 0..31
                int tok = wv * 64 + pf * 16 + l15;       // local token 0..255
                Tep[col * 257 + tok] = pack2(cr[cf][pf][r], ci2[cf][pf][r]);
            }
    __syncthreads();

    const int co_l = t & 31, seg = (t >> 5) << 5;
    u32 vb[32];
#pragma unroll
    for (int j = 0; j < 32; ++j) vb[j] = Tep[co_l * 257 + seg + j];
    const int token0 = row * 256 + seg;

    int co = cog * 32 + co_l;
    int pl = (co < 64) ? 0 : 2;
    int c2 = co & 63;
    u32 rw[16], iw[16];
#pragma unroll
    for (int j = 0; j < 16; ++j) {
        rw[j] = (vb[2 * j] & 0xFFFFu) | (vb[2 * j + 1] << 16);
        iw[j] = (vb[2 * j] >> 16) | (vb[2 * j + 1] & 0xFFFF0000u);
    }
    uint4* dr_ = (uint4*)&dwp[(size_t)(pl * 64 + c2) * HWS + token0];
    uint4* di_ = (uint4*)&dwp[(size_t)((pl + 1) * 64 + c2) * HWS + token0];
#pragma unroll
    for (int j = 0; j < 4; ++j) {
        dr_[j] = make_uint4(rw[4 * j], rw[4 * j + 1], rw[4 * j + 2], rw[4 * j + 3]);
        di_[j] = make_uint4(iw[4 * j], iw[4 * j + 1], iw[4 * j + 2], iw[4 * j + 3]);
    }
}

// ---------------- Kernel C2: q k^T + fused sumsq via MFMA (no LDS) ----------------
__global__ __launch_bounds__(256) void k_qk(const u16* __restrict__ dwp,
                                            float* __restrict__ rnsum,
                                            float* __restrict__ attn,
                                            int b, int SP) {
    const int chunk = blockIdx.x;        // 0..31
    const int d = blockIdx.y;
    const int Kc = SP >> 5;
    const int kc0 = chunk * Kc;
    const u16* qp = dwp + (size_t)d * 64 * SP;
    const u16* kp = dwp + (size_t)(2 + d) * 64 * SP;

    const int t = threadIdx.x, lane = t & 63, wid = t >> 6;
    const int wy = wid >> 1, wx = wid & 1;
    const int l15 = lane & 15, l4 = lane >> 4;

    f32x4 zz = {0.f, 0.f, 0.f, 0.f};
    f32x4 acc[2][2] = {{zz, zz}, {zz, zz}};
    float sq[2] = {0.f, 0.f}, sk[2] = {0.f, 0.f};

    const int iters = Kc >> 5;
    for (int ks = 0; ks < iters; ++ks) {
        int k0 = kc0 + ks * 32 + 8 * l4;
        bf16x8 aq[2], bk[2];
#pragma unroll
        for (int cf = 0; cf < 2; ++cf)
            aq[cf] = *(const bf16x8*)&qp[(size_t)(32 * wy + 16 * cf + l15) * SP + k0];
#pragma unroll
        for (int ef = 0; ef < 2; ++ef)
            bk[ef] = *(const bf16x8*)&kp[(size_t)(32 * wx + 16 * ef + l15) * SP + k0];

        if (wx == 0)
#pragma unroll
            for (int cf = 0; cf < 2; ++cf)
#pragma unroll
                for (int j = 0; j < 8; ++j) {
                    float f = bf2f((u16)aq[cf][j]);
                    sq[cf] = fmaf(f, f, sq[cf]);
                }
        if (wy == 0)
#pragma unroll
            for (int ef = 0; ef < 2; ++ef)
#pragma unroll
                for (int j = 0; j < 8; ++j) {
                    float f = bf2f((u16)bk[ef][j]);
                    sk[ef] = fmaf(f, f, sk[ef]);
                }

#pragma unroll
        for (int cf = 0; cf < 2; ++cf)
#pragma unroll
            for (int ef = 0; ef < 2; ++ef)
                acc[cf][ef] = __builtin_amdgcn_mfma_f32_16x16x32_bf16(aq[cf], bk[ef], acc[cf][ef], 0, 0, 0);
    }

#pragma unroll
    for (int cf = 0; cf < 2; ++cf)
#pragma unroll
        for (int ef = 0; ef < 2; ++ef)
#pragma unroll
            for (int r = 0; r < 4; ++r) {
                int cq = 32 * wy + 16 * cf + 4 * l4 + r;
                int ce = 32 * wx + 16 * ef + l15;
                atomicAdd(&attn[((b * 2 + d) * 64 + cq) * 64 + ce], acc[cf][ef][r]);
            }

    if (wx == 0)
#pragma unroll
        for (int cf = 0; cf < 2; ++cf) {
            float v = sq[cf];
            v += __shfl_xor(v, 16);
            v += __shfl_xor(v, 32);
            if (lane < 16)
                atomicAdd(&rnsum[((size_t)b * 128 + 32 * wy + 16 * cf + lane) * 2 + d], v);
        }
    if (wy == 0)
#pragma unroll
        for (int ef = 0; ef < 2; ++ef) {
            float v = sk[ef];
            v += __shfl_xor(v, 16);
            v += __shfl_xor(v, 32);
            if (lane < 16)
                atomicAdd(&rnsum[((size_t)b * 128 + 64 + 32 * wx + 16 * ef + lane) * 2 + d], v);
        }
}

// ---------------- Kernel D1: scale + row softmax -> P ----------------
__global__ __launch_bounds__(64) void k_prob(const float* __restrict__ attn,
                                             const float* __restrict__ rnsum,
                                             float* __restrict__ P, int b) {
    int d = blockIdx.x;
    int t = threadIdx.x;
    __shared__ float rks[64];
    float sk = rnsum[((size_t)b * 128 + 64 + t) * 2 + d];
    rks[t] = 1.0f / fmaxf(sqrtf(sk), 1e-12f);
    float sq = rnsum[((size_t)b * 128 + t) * 2 + d];
    float rq = 1.0f / fmaxf(sqrtf(sq), 1e-12f);
    __syncthreads();

    const float* arow = attn + ((size_t)(b * 2 + d) * 64 + t) * 64;
    float v[64];
    float m = -1e30f;
#pragma unroll
    for (int e = 0; e < 64; ++e) { v[e] = arow[e] * rq * rks[e]; m = fmaxf(m, v[e]); }
    float ssum = 0.f;
#pragma unroll
    for (int e = 0; e < 64; ++e) { v[e] = __expf(v[e] - m); ssum += v[e]; }
    float r = 1.0f / ssum;
    float* prow = P + ((size_t)(b * 2 + d) * 64 + t) * 64;
#pragma unroll
    for (int e = 0; e < 64; ++e) prow[e] = v[e] * r;
}

// ---------------- Kernel D2: build A_big from P and proj weights ----------------
__global__ __launch_bounds__(256) void k_M(const float* __restrict__ P,
                                           const float* __restrict__ pwr,
                                           const float* __restrict__ pwi,
                                           u16* __restrict__ Abig, int b) {
    int pair = blockIdx.x * 256 + threadIdx.x;   // 0..4095
    __shared__ float P0[64][64], P1[64][64];
    __shared__ float Wr[64][64], Wi2[64][64];
    for (int i = threadIdx.x; i < 4096; i += 256) {
        P0[i >> 6][i & 63] = P[(size_t)(b * 2 + 0) * 4096 + i];
        P1[i >> 6][i & 63] = P[(size_t)(b * 2 + 1) * 4096 + i];
        Wr[i >> 6][i & 63] = pwr[i];
        Wi2[i >> 6][i & 63] = pwi[i];
    }
    __syncthreads();
    int co = pair >> 6, e = pair & 63;
    float m1 = 0.f, m2 = 0.f, m3 = 0.f, m4 = 0.f;
#pragma unroll 8
    for (int c = 0; c < 64; ++c) {
        float pr = Wr[co][c], pi = Wi2[co][c];
        float a0 = P0[c][e], a1 = P1[c][e];
        m1 = fmaf(pr, a0, m1);
        m2 = fmaf(pi, a1, m2);
        m3 = fmaf(pr, a1, m3);
        m4 = fmaf(pi, a0, m4);
    }
    u16* AB = Abig + (size_t)b * 16384;
    AB[(2 * co) * 128 + 2 * e]         = f2bf(m1);
    AB[(2 * co) * 128 + 2 * e + 1]     = f2bf(-m2);
    AB[(2 * co + 1) * 128 + 2 * e]     = f2bf(m4);
    AB[(2 * co + 1) * 128 + 2 * e + 1] = f2bf(m3);
}

// ---------------- Kernel F: out = A_big * vT via MFMA (no LDS) ----------------
__global__ __launch_bounds__(256) void k_out(const u16* __restrict__ Abig,
                                             const u16* __restrict__ vT,
                                             float* __restrict__ outb) {
    const int p0 = blockIdx.x << 6;
    const int t = threadIdx.x, lane = t & 63, w = t >> 6;
    const int l15 = lane & 15, l4 = lane >> 4;

    bf16x8 Af[2][4];
#pragma unroll
    for (int cf = 0; cf < 2; ++cf)
#pragma unroll
        for (int ks = 0; ks < 4; ++ks)
            Af[cf][ks] = *(const bf16x8*)&Abig[(size_t)(32 * w + 16 * cf + l15) * 128 + 32 * ks + 8 * l4];

    f32x4 zz = {0.f, 0.f, 0.f, 0.f};
    f32x4 acc[2][4];
#pragma unroll
    for (int cf = 0; cf < 2; ++cf)
#pragma unroll
        for (int nf = 0; nf < 4; ++nf) acc[cf][nf] = zz;

#pragma unroll
    for (int ks = 0; ks < 4; ++ks) {
        bf16x8 Bf[4];
#pragma unroll
        for (int nf = 0; nf < 4; ++nf)
            Bf[nf] = *(const bf16x8*)&vT[(size_t)(p0 + 16 * nf + l15) * 128 + 32 * ks + 8 * l4];
#pragma unroll
        for (int cf = 0; cf < 2; ++cf)
#pragma unroll
            for (int nf = 0; nf < 4; ++nf)
                acc[cf][nf] = __builtin_amdgcn_mfma_f32_16x16x32_bf16(Af[cf][ks], Bf[nf], acc[cf][nf], 0, 0, 0);
    }

    float2* o2 = (float2*)outb;
#pragma unroll
    for (int cf = 0; cf < 2; ++cf)
#pragma unroll
        for (int nf = 0; nf < 4; ++nf) {
            int co = 16 * w + 8 * cf + 2 * l4;
            int p = p0 + 16 * nf + l15;
            o2[(size_t)co * HWS + p]       = make_float2(acc[cf][nf][0], acc[cf][nf][1]);
            o2[(size_t)(co + 1) * HWS + p] = make_float2(acc[cf][nf][2], acc[cf][nf][3]);
        }
}

extern "C" void kernel_launch(void* const* d_in, const int* in_sizes, int n_in,
                              void* d_out, int out_size, void* d_ws, size_t ws_size,
                              hipStream_t stream) {
    const float* x      = (const float*)d_in[0];
    const float* qkv_wr = (const float*)d_in[1];
    const float* qkv_wi = (const float*)d_in[2];
    const float* dw_wr  = (const float*)d_in[3];
    const float* dw_wi  = (const float*)d_in[4];
    const float* p_wr   = (const float*)d_in[5];
    const float* p_wi   = (const float*)d_in[6];
    float* out = (float*)d_out;

    // workspace (~68.1 MB)
    char* base = (char*)d_ws;
    const size_t xt_sz = (size_t)PIT * PIT * 64 * 2;       // 8,520,192 B per plane
    u16*   dwp  = (u16*)base;                              // 33,554,432 B
    u16*   xTr  = (u16*)(base + 33554432);
    u16*   xTi  = (u16*)(base + 33554432 + xt_sz);
    u32*   vT   = (u32*)(base + 33554432 + 2 * xt_sz);     // 16,777,216 B
    u16*   WB   = (u16*)(base + 33554432 + 2 * xt_sz + 16777216);   // 663,552 B
    float* rnsum = (float*)((char*)WB + 663552);
    float* attn  = rnsum + 512;
    float* Pbuf  = attn + 16384;
    u16*   Abig  = (u16*)(Pbuf + 16384);

    k_fold<<<432, 256, 0, stream>>>(qkv_wr, qkv_wi, dw_wr, dw_wi, WB);
    k_zero<<<66, 256, 0, stream>>>(rnsum, 512 + 16384);
    k_border<<<33, 256, 0, stream>>>(xTr, xTi);

    for (int b = 0; b < 2; ++b) {
        const float* xb = x + (size_t)b * 64 * HWS * 2;
        k_xt<<<1024, 256, 0, stream>>>(xb, xTr, xTi);
        k_conv<<<1536, 256, 0, stream>>>(xTr, xTi, WB, dwp, vT);
        k_qk<<<dim3(32, 2), 256, 0, stream>>>(dwp, rnsum, attn, b, HWS);
        k_prob<<<2, 64, 0, stream>>>(attn, rnsum, Pbuf, b);
        k_M<<<16, 256, 0, stream>>>(Pbuf, p_wr, p_wi, Abig, b);
        k_out<<<1024, 256, 0, stream>>>(Abig + (size_t)b * 16384, (const u16*)vT,
                                        out + (size_t)b * 64 * HWS * 2);
    }
}